// Round 12
// baseline (315.531 us; speedup 1.0000x reference)
//
#include <hip/hip_runtime.h>
#include <hip/hip_bf16.h>
#include <math.h>

// GCN 2-layer: h = Ddst^-1/2 A (Dsrc^-1/2 x) W + b, relu between.
// R21: revert R20's overlap (ns-in-gather added +50MB scattered norm loads
// to spmm1's critical path: 74us, FETCH 135MB — overlap gain ~3us didn't
// cover it). Back to R19 ordering; attack the gathers' MLP instead:
//  - spmm1: 16 lanes/node x 16B (ushort8) loads, 32 nodes/512-thr block,
//    2-wave MFMA projection. 2x rows in flight/wave, 4 blocks/CU.
//  - spmm2: 5 lanes/node x 16B loads, 50 nodes/block.
// (R20 profile: spmm1 is the largest controllable kernel, 25% BW / 51% occ
// / 21% VALU = latency-bound -> MLP+occupancy is the right lever.)
// LEDGER (R11/R17): hipcc sinks hoisted global loads -> LDS staging for B.
// (R14): device-scope atomicAdd is HBM write-through -> histogram CSR build.
// 2x400MB harness poison fills (~119us) sit inside the timed window.

#define F_IN  256
#define F_HID 128
#define F_CLS 40

#define RSZ 8192    // nodes per histogram range (32KB LDS)
#define NSL 32      // edge slices

typedef __bf16 bf16_t;
typedef bf16_t bf16x8 __attribute__((ext_vector_type(8)));
typedef float floatx4 __attribute__((ext_vector_type(4)));
typedef _Float16 f16x8 __attribute__((ext_vector_type(8)));
typedef unsigned short ushort8v __attribute__((ext_vector_type(8)));

static __device__ __forceinline__ unsigned short f2b(float f) {
    __hip_bfloat16 h = __float2bfloat16(f);   // RNE
    return __builtin_bit_cast(unsigned short, h);
}
static __device__ __forceinline__ float b2f(unsigned short u) {
    return __uint_as_float((unsigned)u << 16);
}
static __device__ __forceinline__ unsigned short f2h(float f) {
    return __builtin_bit_cast(unsigned short, (_Float16)f);
}
static __device__ __forceinline__ float h2f(unsigned short u) {
    return (float)__builtin_bit_cast(_Float16, u);
}

// ---- histogram partials: block (r, sl, y) counts keys-in-range from slice --
__global__ __launch_bounds__(256) void hist_kernel(
    const int* __restrict__ src, const int* __restrict__ dst,
    unsigned* __restrict__ partial_s, unsigned* __restrict__ partial_d, int E)
{
    __shared__ unsigned h[RSZ];
    const int t = threadIdx.x;
    const int r  = blockIdx.x / NSL;
    const int sl = blockIdx.x % NSL;
    const int lo = r * RSZ;
    const int* __restrict__ keys = blockIdx.y ? dst : src;
    unsigned* __restrict__ part = blockIdx.y ? partial_d : partial_s;

    for (int i = t; i < RSZ; i += 256) h[i] = 0;
    __syncthreads();

    const int slice = (E + NSL - 1) / NSL;
    const int e0 = sl * slice;
    const int e1 = min(E, e0 + slice);

    int e = e0 + t;
    for (; e + 7 * 256 < e1; e += 8 * 256) {
        int k[8];
        #pragma unroll
        for (int i = 0; i < 8; ++i) k[i] = keys[e + i * 256];
        #pragma unroll
        for (int i = 0; i < 8; ++i) {
            unsigned kk = (unsigned)(k[i] - lo);
            if (kk < RSZ) atomicAdd(&h[kk], 1u);
        }
    }
    for (; e < e1; e += 256) {
        unsigned kk = (unsigned)(keys[e] - lo);
        if (kk < RSZ) atomicAdd(&h[kk], 1u);
    }
    __syncthreads();

    unsigned* dst_p = part + (size_t)blockIdx.x * RSZ;
    for (int i = t; i < RSZ; i += 256) dst_p[i] = h[i];
}

// ---- scan1: reduce partials -> norms + block-local exclusive scan ----------
__global__ __launch_bounds__(256) void scan1_kernel(
    const unsigned* __restrict__ partial_s, const unsigned* __restrict__ partial_d,
    int* __restrict__ row_off, int* __restrict__ blk_sums,
    float* __restrict__ norm_src, float* __restrict__ norm_dst, int N)
{
    __shared__ int s[256];
    const int t = threadIdx.x;
    const int base = blockIdx.x * 1024 + t * 4;

    unsigned ss0 = 0, ss1 = 0, ss2 = 0, ss3 = 0;
    unsigned sd0 = 0, sd1 = 0, sd2 = 0, sd3 = 0;
    {
        // base..base+3 never cross an RSZ boundary (both multiples of 4)
        const int r = base / RSZ;
        const int off = base & (RSZ - 1);
        const unsigned* ps = partial_s + (size_t)r * NSL * RSZ + off;
        const unsigned* pd = partial_d + (size_t)r * NSL * RSZ + off;
        #pragma unroll
        for (int sl = 0; sl < NSL; ++sl) {
            uint4 a = *(const uint4*)(ps + (size_t)sl * RSZ);
            uint4 b = *(const uint4*)(pd + (size_t)sl * RSZ);
            ss0 += a.x; ss1 += a.y; ss2 += a.z; ss3 += a.w;
            sd0 += b.x; sd1 += b.y; sd2 += b.z; sd3 += b.w;
        }
    }
    if (base + 0 < N) {
        norm_src[base + 0] = ss0 ? 1.0f / sqrtf((float)ss0) : 0.0f;
        norm_dst[base + 0] = sd0 ? 1.0f / sqrtf((float)sd0) : 0.0f;
    }
    if (base + 1 < N) {
        norm_src[base + 1] = ss1 ? 1.0f / sqrtf((float)ss1) : 0.0f;
        norm_dst[base + 1] = sd1 ? 1.0f / sqrtf((float)sd1) : 0.0f;
    }
    if (base + 2 < N) {
        norm_src[base + 2] = ss2 ? 1.0f / sqrtf((float)ss2) : 0.0f;
        norm_dst[base + 2] = sd2 ? 1.0f / sqrtf((float)sd2) : 0.0f;
    }
    if (base + 3 < N) {
        norm_src[base + 3] = ss3 ? 1.0f / sqrtf((float)ss3) : 0.0f;
        norm_dst[base + 3] = sd3 ? 1.0f / sqrtf((float)sd3) : 0.0f;
    }

    int v0 = (base + 0 < N) ? (int)sd0 : 0;
    int v1 = (base + 1 < N) ? (int)sd1 : 0;
    int v2 = (base + 2 < N) ? (int)sd2 : 0;
    int v3 = (base + 3 < N) ? (int)sd3 : 0;
    int local = v0 + v1 + v2 + v3;
    s[t] = local;
    __syncthreads();
    for (int off = 1; off < 256; off <<= 1) {
        int x = (t >= off) ? s[t - off] : 0;
        __syncthreads();
        s[t] += x;
        __syncthreads();
    }
    int excl = s[t] - local;
    if (t == 255) blk_sums[blockIdx.x] = s[t];
    if (base + 0 < N) row_off[base + 0] = excl;
    if (base + 1 < N) row_off[base + 1] = excl + v0;
    if (base + 2 < N) row_off[base + 2] = excl + v0 + v1;
    if (base + 3 < N) row_off[base + 3] = excl + v0 + v1 + v2;
}

// ---- scan2 (block 0) + pack W1->W1t (blocks 1..128) + W2->W2t (129..152) ---
__global__ __launch_bounds__(256) void scan2_pack_kernel(
    int* __restrict__ blk_sums, int B,
    const float* __restrict__ W1, __hip_bfloat16* __restrict__ W1t,
    const float* __restrict__ W2, unsigned short* __restrict__ W2t)
{
    const int t = threadIdx.x;
    if (blockIdx.x > 128) {
        int idx = (blockIdx.x - 129) * 256 + t;   // 0..6143
        int n = idx >> 7;                         // 0..47
        int k = idx & 127;
        W2t[idx] = (n < F_CLS) ? f2h(W2[(size_t)k * F_CLS + n]) : (unsigned short)0;
        return;
    }
    if (blockIdx.x > 0) {
        int idx = (blockIdx.x - 1) * 256 + t;     // 0..32767
        int n = idx >> 8;
        int k = idx & 255;
        W1t[idx] = __float2bfloat16(W1[(size_t)k * F_HID + n]);
        return;
    }
    __shared__ int s[256];
    int local = (t < B) ? blk_sums[t] : 0;
    s[t] = local;
    __syncthreads();
    for (int off = 1; off < 256; off <<= 1) {
        int x = (t >= off) ? s[t - off] : 0;
        __syncthreads();
        s[t] += x;
        __syncthreads();
    }
    if (t < B) blk_sums[t] = s[t] - local;   // exclusive
}

// ---- scan3+slicepref fused ------------------------------------------------
__global__ __launch_bounds__(256) void scan3_slicepref_kernel(
    int* __restrict__ row_off, const int* __restrict__ blk_sums,
    unsigned* __restrict__ partial_d, int N, int E, int NRtot)
{
    const int idx = blockIdx.x * 256 + threadIdx.x;   // node id (incl. pad)
    if (idx >= NRtot) return;
    unsigned run = 0;
    if (idx < N) {
        int v = row_off[idx] + blk_sums[idx >> 10];
        row_off[idx] = v;
        run = (unsigned)v;
    }
    if (idx == N) row_off[N] = E;
    const int r = idx / RSZ;
    const int i = idx & (RSZ - 1);
    unsigned* p = partial_d + (size_t)r * NSL * RSZ + i;
    #pragma unroll
    for (int sl = 0; sl < NSL; ++sl) {
        unsigned c = p[(size_t)sl * RSZ];
        p[(size_t)sl * RSZ] = run;
        run += c;
    }
}

// ---- scatter edges into CSR via LDS cursors (no global atomics) ------------
__global__ __launch_bounds__(256) void scatter2_kernel(
    const int* __restrict__ src, const int* __restrict__ dst,
    const unsigned* __restrict__ pref, int* __restrict__ csr_src, int E)
{
    __shared__ unsigned cur[RSZ];
    const int t = threadIdx.x;
    const int r  = blockIdx.x / NSL;
    const int sl = blockIdx.x % NSL;
    const int lo = r * RSZ;
    const unsigned* p = pref + (size_t)blockIdx.x * RSZ;   // [r][sl][.]

    for (int i = t; i < RSZ; i += 256) cur[i] = p[i];
    __syncthreads();

    const int slice = (E + NSL - 1) / NSL;
    const int e0 = sl * slice;
    const int e1 = min(E, e0 + slice);

    int e = e0 + t;
    for (; e + 7 * 256 < e1; e += 8 * 256) {
        int d[8], s[8];
        #pragma unroll
        for (int i = 0; i < 8; ++i) { d[i] = dst[e + i * 256]; s[i] = src[e + i * 256]; }
        #pragma unroll
        for (int i = 0; i < 8; ++i) {
            unsigned k = (unsigned)(d[i] - lo);
            if (k < RSZ) {
                unsigned pos = atomicAdd(&cur[k], 1u);
                csr_src[pos] = s[i];
            }
        }
    }
    for (; e < e1; e += 256) {
        unsigned k = (unsigned)(dst[e] - lo);
        if (k < RSZ) {
            unsigned pos = atomicAdd(&cur[k], 1u);
            csr_src[pos] = src[e];
        }
    }
}

// ---- GEMM1 (MFMA): h1b[N,128] = bf16( (X @ W1)*ns ) ------------------------
// R12 structure + R19 2-deep X prefetch; ns applied in fp32 epilogue.
__global__ __launch_bounds__(512, 4) void gemm1_mfma_kernel(
    const float* __restrict__ X, const __hip_bfloat16* __restrict__ W1t,
    const float* __restrict__ norm_src, __hip_bfloat16* __restrict__ h1b, int N)
{
    __shared__ __hip_bfloat16 Bs[128 * 256];   // 64KB, rows XOR-swizzled
    const int t = threadIdx.x;
    const int node0 = blockIdx.x * 128;
    const int lane = t & 63;
    const int w = t >> 6;               // wave 0..7 -> 16 rows each
    const int l15 = lane & 15;
    const int quad = lane >> 4;

    const int arow = node0 + w * 16 + l15;
    const int arow_c = (arow < N) ? arow : (N - 1);
    const float* xp = X + (size_t)arow_c * F_IN + quad * 8;

    float4 ar[2][4];
    ar[0][0] = *(const float4*)(xp + 0);
    ar[0][1] = *(const float4*)(xp + 4);
    ar[0][2] = *(const float4*)(xp + 32);
    ar[0][3] = *(const float4*)(xp + 36);
    ar[1][0] = *(const float4*)(xp + 64 + 0);
    ar[1][1] = *(const float4*)(xp + 64 + 4);
    ar[1][2] = *(const float4*)(xp + 64 + 32);
    ar[1][3] = *(const float4*)(xp + 64 + 36);

    #pragma unroll
    for (int i = 0; i < 8; ++i) {
        int idx = i * 512 + t;
        int row = idx >> 5;             // 0..127
        int ch  = idx & 31;             // 16B chunk within row
        uint4 v = *(const uint4*)(W1t + (size_t)row * F_IN + ch * 8);
        int d = row * 256 + ((ch * 8) ^ ((row & 7) << 3));
        *(uint4*)(Bs + d) = v;
    }
    __syncthreads();

    const int swz = (l15 & 7) << 3;
    const int bbase0 = l15 * 256 + ((quad * 8) ^ swz);
    const int bbase1 = l15 * 256 + ((32 + quad * 8) ^ swz);

    floatx4 acc[8] = {};

    #pragma unroll
    for (int c = 0; c < 4; ++c) {
        const int p = c & 1;
        bf16x8 ab0, ab1;
        {
            union { bf16x8 v; unsigned short u[8]; } cv;
            cv.u[0] = f2b(ar[p][0].x); cv.u[1] = f2b(ar[p][0].y);
            cv.u[2] = f2b(ar[p][0].z); cv.u[3] = f2b(ar[p][0].w);
            cv.u[4] = f2b(ar[p][1].x); cv.u[5] = f2b(ar[p][1].y);
            cv.u[6] = f2b(ar[p][1].z); cv.u[7] = f2b(ar[p][1].w);
            ab0 = cv.v;
            cv.u[0] = f2b(ar[p][2].x); cv.u[1] = f2b(ar[p][2].y);
            cv.u[2] = f2b(ar[p][2].z); cv.u[3] = f2b(ar[p][2].w);
            cv.u[4] = f2b(ar[p][3].x); cv.u[5] = f2b(ar[p][3].y);
            cv.u[6] = f2b(ar[p][3].z); cv.u[7] = f2b(ar[p][3].w);
            ab1 = cv.v;
        }
        if (c < 2) {
            ar[p][0] = *(const float4*)(xp + (c + 2) * 64 + 0);
            ar[p][1] = *(const float4*)(xp + (c + 2) * 64 + 4);
            ar[p][2] = *(const float4*)(xp + (c + 2) * 64 + 32);
            ar[p][3] = *(const float4*)(xp + (c + 2) * 64 + 36);
        }
        #pragma unroll
        for (int nt = 0; nt < 8; ++nt) {
            bf16x8 b = *(const bf16x8*)(Bs + bbase0 + nt * 16 * 256 + c * 64);
            acc[nt] = __builtin_amdgcn_mfma_f32_16x16x32_bf16(ab0, b, acc[nt], 0, 0, 0);
        }
        #pragma unroll
        for (int nt = 0; nt < 8; ++nt) {
            bf16x8 b = *(const bf16x8*)(Bs + bbase1 + nt * 16 * 256 + c * 64);
            acc[nt] = __builtin_amdgcn_mfma_f32_16x16x32_bf16(ab1, b, acc[nt], 0, 0, 0);
        }
    }

    #pragma unroll
    for (int r = 0; r < 4; ++r) {
        int node = node0 + w * 16 + quad * 4 + r;
        if (node < N) {
            float ns = norm_src[node];
            #pragma unroll
            for (int nt = 0; nt < 8; ++nt)
                h1b[(size_t)node * F_HID + nt * 16 + l15] =
                    __float2bfloat16(acc[nt][r] * ns);
        }
    }
}

// ---- SpMM1 + layer-1 epilogue + fused MFMA projection to h2 ----------------
// R21: 32 nodes/block (512 thr), 16 lanes/node, 16B (ushort8) gathers —
// 2x rows in flight per wave vs R19. As[32][136] fp16; 2 waves each project
// 16 rows via 12x mfma_f32_16x16x32_f16 (B = W2t[48][128] from L2).
__global__ __launch_bounds__(512) void spmm1_fused_kernel(
    const __hip_bfloat16* __restrict__ h1b, const int* __restrict__ row_off,
    const int* __restrict__ csr_src, const float* __restrict__ norm_src,
    const float* __restrict__ norm_dst, const float* __restrict__ b1,
    const unsigned short* __restrict__ W2t, unsigned short* __restrict__ h2, int N)
{
    __shared__ unsigned short As[32][136];
    const int t = threadIdx.x;
    const int g = t >> 4;               // node group 0..31
    const int node = blockIdx.x * 32 + g;
    const int c = (t & 15) << 3;        // 8-element (16B) column offset

    if (node < N) {
        const int start = row_off[node];
        const int end = row_off[node + 1];
        float acc[8] = {};
        int j = start;
        for (; j + 8 <= end; j += 8) {
            int s[8];
            #pragma unroll
            for (int i = 0; i < 8; ++i) s[i] = csr_src[j + i];
            ushort8v u[8];
            #pragma unroll
            for (int i = 0; i < 8; ++i)
                u[i] = *(const ushort8v*)(h1b + (size_t)s[i] * F_HID + c);
            #pragma unroll
            for (int i = 0; i < 8; ++i) {
                #pragma unroll
                for (int k = 0; k < 8; ++k) acc[k] += b2f(u[i][k]);
            }
        }
        for (; j < end; ++j) {
            int s = csr_src[j];
            ushort8v u = *(const ushort8v*)(h1b + (size_t)s * F_HID + c);
            #pragma unroll
            for (int k = 0; k < 8; ++k) acc[k] += b2f(u[k]);
        }
        const float nd = norm_dst[node];
        const float ns = norm_src[node];
        float4 bb0 = *(const float4*)(b1 + c);
        float4 bb1 = *(const float4*)(b1 + c + 4);
        ushort8v o;
        o[0] = f2h(fmaxf(fmaf(acc[0], nd, bb0.x), 0.f) * ns);
        o[1] = f2h(fmaxf(fmaf(acc[1], nd, bb0.y), 0.f) * ns);
        o[2] = f2h(fmaxf(fmaf(acc[2], nd, bb0.z), 0.f) * ns);
        o[3] = f2h(fmaxf(fmaf(acc[3], nd, bb0.w), 0.f) * ns);
        o[4] = f2h(fmaxf(fmaf(acc[4], nd, bb1.x), 0.f) * ns);
        o[5] = f2h(fmaxf(fmaf(acc[5], nd, bb1.y), 0.f) * ns);
        o[6] = f2h(fmaxf(fmaf(acc[6], nd, bb1.z), 0.f) * ns);
        o[7] = f2h(fmaxf(fmaf(acc[7], nd, bb1.w), 0.f) * ns);
        *(ushort8v*)&As[g][c] = o;
    } else {
        ushort8v z = {0, 0, 0, 0, 0, 0, 0, 0};
        *(ushort8v*)&As[g][c] = z;
    }
    __syncthreads();
    if (t >= 128) return;

    const int wv = t >> 6;              // 0,1 -> rows wv*16..wv*16+15
    const int lane = t & 63;
    const int l15 = lane & 15;
    const int quad = lane >> 4;
    floatx4 co[3] = {};
    #pragma unroll
    for (int kc = 0; kc < 4; ++kc) {
        f16x8 a = *(const f16x8*)&As[wv * 16 + l15][kc * 32 + quad * 8];
        #pragma unroll
        for (int ct = 0; ct < 3; ++ct) {
            f16x8 b = *(const f16x8*)(W2t + (size_t)(ct * 16 + l15) * F_HID
                                          + kc * 32 + quad * 8);
            co[ct] = __builtin_amdgcn_mfma_f32_16x16x32_f16(a, b, co[ct], 0, 0, 0);
        }
    }
    const int node0 = blockIdx.x * 32 + wv * 16;
    #pragma unroll
    for (int ct = 0; ct < 3; ++ct) {
        int col = ct * 16 + l15;
        if (col < F_CLS) {
            #pragma unroll
            for (int i = 0; i < 4; ++i) {
                int n2 = node0 + quad * 4 + i;
                if (n2 < N) h2[(size_t)n2 * F_CLS + col] = f2h(co[ct][i]);
            }
        }
    }
}

// ---- SpMM2 (CSR, fp16 gather) + epilogue: out = (sum h2[src,:])*nd + b2 ----
// R21: 50 nodes/block, 5 lanes/node, 16B (ushort8) gathers (250/256 active).
__global__ __launch_bounds__(256) void spmm2_csr_kernel(
    const unsigned short* __restrict__ h2, const int* __restrict__ row_off,
    const int* __restrict__ csr_src, const float* __restrict__ norm_dst,
    const float* __restrict__ b2, float* __restrict__ out, int N)
{
    const int t = threadIdx.x;
    if (t >= 250) return;
    const int node = blockIdx.x * 50 + t / 5;
    const int lane = t % 5;
    if (node >= N) return;
    const int c = lane << 3;            // 8 fp16 elements = 16B
    const int start = row_off[node];
    const int end = row_off[node + 1];
    float acc[8] = {};
    int j = start;
    for (; j + 8 <= end; j += 8) {
        int s[8];
        #pragma unroll
        for (int i = 0; i < 8; ++i) s[i] = csr_src[j + i];
        ushort8v u[8];
        #pragma unroll
        for (int i = 0; i < 8; ++i)
            u[i] = *(const ushort8v*)(h2 + (size_t)s[i] * F_CLS + c);
        #pragma unroll
        for (int i = 0; i < 8; ++i) {
            #pragma unroll
            for (int k = 0; k < 8; ++k) acc[k] += h2f(u[i][k]);
        }
    }
    for (; j < end; ++j) {
        int s = csr_src[j];
        ushort8v u = *(const ushort8v*)(h2 + (size_t)s * F_CLS + c);
        #pragma unroll
        for (int k = 0; k < 8; ++k) acc[k] += h2f(u[k]);
    }
    float nd = norm_dst[node];
    float4 bb0 = *(const float4*)(b2 + c);
    float4 bb1 = *(const float4*)(b2 + c + 4);
    float4 r0, r1;
    r0.x = fmaf(acc[0], nd, bb0.x);
    r0.y = fmaf(acc[1], nd, bb0.y);
    r0.z = fmaf(acc[2], nd, bb0.z);
    r0.w = fmaf(acc[3], nd, bb0.w);
    r1.x = fmaf(acc[4], nd, bb1.x);
    r1.y = fmaf(acc[5], nd, bb1.y);
    r1.z = fmaf(acc[6], nd, bb1.z);
    r1.w = fmaf(acc[7], nd, bb1.w);
    float* op = out + (size_t)node * F_CLS + c;
    *(float4*)(op + 0) = r0;
    *(float4*)(op + 4) = r1;
}

extern "C" void kernel_launch(void* const* d_in, const int* in_sizes, int n_in,
                              void* d_out, int out_size, void* d_ws, size_t ws_size,
                              hipStream_t stream) {
    const float* X   = (const float*)d_in[0];
    const int*   src = (const int*)d_in[1];
    const int*   dst = (const int*)d_in[2];
    const float* W1  = (const float*)d_in[3];
    const float* b1  = (const float*)d_in[4];
    const float* W2  = (const float*)d_in[5];
    const float* b2  = (const float*)d_in[6];
    float* out = (float*)d_out;

    const int N = in_sizes[0] / F_IN;
    const int E = in_sizes[1];
    const int NB = (N + 1023) / 1024;     // scan blocks (<= 256)
    const int NR = (N + RSZ - 1) / RSZ;   // histogram ranges
    const int NRtot = NR * RSZ;

    // workspace layout — keep every array 16B-aligned
    char* w = (char*)d_ws;
    int*   row_off  = (int*)w;                      w += (size_t)(N + 4) * 4;
    int*   blk_sums = (int*)w;                      w += 256 * 4;
    int*   csr_src  = (int*)w;                      w += (size_t)E * 4;
    float* norm_src = (float*)w;                    w += (size_t)N * 4;
    float* norm_dst = (float*)w;                    w += (size_t)N * 4;
    unsigned short* h2 = (unsigned short*)w;        w += (size_t)N * F_CLS * 2;
    __hip_bfloat16* W1t = (__hip_bfloat16*)w;       w += (size_t)F_HID * F_IN * 2;
    unsigned short* W2t = (unsigned short*)w;       w += (size_t)48 * F_HID * 2;
    __hip_bfloat16* h1b = (__hip_bfloat16*)w;       w += (size_t)N * F_HID * 2;
    unsigned* partial_s = (unsigned*)w;             w += (size_t)NR * NSL * RSZ * 4;
    unsigned* partial_d = (unsigned*)w;             w += (size_t)NR * NSL * RSZ * 4;

    hist_kernel<<<dim3(NR * NSL, 2), 256, 0, stream>>>(src, dst, partial_s, partial_d, E);

    scan1_kernel<<<NB, 256, 0, stream>>>(partial_s, partial_d, row_off, blk_sums,
                                         norm_src, norm_dst, N);
    scan2_pack_kernel<<<153, 256, 0, stream>>>(blk_sums, NB, W1, W1t, W2, W2t);
    scan3_slicepref_kernel<<<(NRtot + 255) / 256, 256, 0, stream>>>(
        row_off, blk_sums, partial_d, N, E, NRtot);

    scatter2_kernel<<<NR * NSL, 256, 0, stream>>>(src, dst, partial_d, csr_src, E);

    gemm1_mfma_kernel<<<(N + 127) / 128, 512, 0, stream>>>(X, W1t, norm_src, h1b, N);

    spmm1_fused_kernel<<<(N + 31) / 32, 512, 0, stream>>>(h1b, row_off, csr_src,
                                                          norm_src, norm_dst, b1,
                                                          W2t, h2, N);

    spmm2_csr_kernel<<<(N + 49) / 50, 256, 0, stream>>>(h2, row_off, csr_src,
                                                        norm_dst, b2, out, N);
}

// Round 13
// 301.251 us; speedup vs baseline: 1.0474x; 1.0474x over previous
//
#include <hip/hip_runtime.h>
#include <hip/hip_bf16.h>
#include <math.h>

// GCN 2-layer: h = Ddst^-1/2 A (Dsrc^-1/2 x) W + b, relu between.
// R22: RESTORE the session-best R19 configuration (measured 299.7us).
// R21's spmm lane-geometry change regressed (spmm1 65.6us, occ 34%,
// intra-wave imbalance with 4 nodes/wave); R20's overlap regressed
// (ns-in-gather +50MB scattered loads). Both reverted.
// Final structure: histogram CSR build (deterministic, L2-resident edge
// re-reads) -> fused scans -> LDS-cursor scatter; gemm1 = single-barrier
// 64KB-LDS MFMA with 2-deep X prefetch + epilogue ns; spmm1 = CSR gather
// (32 lanes/node) + fused relu/norm epilogue + 1-wave MFMA projection to
// h2 fp16 (gemm2 eliminated); spmm2 = fp16 gather + epilogue.
// LEDGER: (R11/R17) hipcc sinks hoisted global loads -> LDS staging for B.
// (R14) device-scope atomicAdd is HBM write-through (~32B/op). (R20/R21)
// spmm1 gather = ~130MB inherent L2-miss traffic, latency-floor ~55us.
// 2x400MB harness poison fills (~119us) sit inside the timed window.

#define F_IN  256
#define F_HID 128
#define F_CLS 40

#define RSZ 8192    // nodes per histogram range (32KB LDS)
#define NSL 32      // edge slices

typedef __bf16 bf16_t;
typedef bf16_t bf16x8 __attribute__((ext_vector_type(8)));
typedef float floatx4 __attribute__((ext_vector_type(4)));
typedef _Float16 f16x8 __attribute__((ext_vector_type(8)));

static __device__ __forceinline__ unsigned short f2b(float f) {
    __hip_bfloat16 h = __float2bfloat16(f);   // RNE
    return __builtin_bit_cast(unsigned short, h);
}
static __device__ __forceinline__ float b2f(unsigned short u) {
    return __uint_as_float((unsigned)u << 16);
}
static __device__ __forceinline__ unsigned short f2h(float f) {
    return __builtin_bit_cast(unsigned short, (_Float16)f);
}
static __device__ __forceinline__ float h2f(unsigned short u) {
    return (float)__builtin_bit_cast(_Float16, u);
}

// ---- histogram partials: block (r, sl, y) counts keys-in-range from slice --
__global__ __launch_bounds__(256) void hist_kernel(
    const int* __restrict__ src, const int* __restrict__ dst,
    unsigned* __restrict__ partial_s, unsigned* __restrict__ partial_d, int E)
{
    __shared__ unsigned h[RSZ];
    const int t = threadIdx.x;
    const int r  = blockIdx.x / NSL;
    const int sl = blockIdx.x % NSL;
    const int lo = r * RSZ;
    const int* __restrict__ keys = blockIdx.y ? dst : src;
    unsigned* __restrict__ part = blockIdx.y ? partial_d : partial_s;

    for (int i = t; i < RSZ; i += 256) h[i] = 0;
    __syncthreads();

    const int slice = (E + NSL - 1) / NSL;
    const int e0 = sl * slice;
    const int e1 = min(E, e0 + slice);

    int e = e0 + t;
    for (; e + 7 * 256 < e1; e += 8 * 256) {
        int k[8];
        #pragma unroll
        for (int i = 0; i < 8; ++i) k[i] = keys[e + i * 256];
        #pragma unroll
        for (int i = 0; i < 8; ++i) {
            unsigned kk = (unsigned)(k[i] - lo);
            if (kk < RSZ) atomicAdd(&h[kk], 1u);
        }
    }
    for (; e < e1; e += 256) {
        unsigned kk = (unsigned)(keys[e] - lo);
        if (kk < RSZ) atomicAdd(&h[kk], 1u);
    }
    __syncthreads();

    unsigned* dst_p = part + (size_t)blockIdx.x * RSZ;
    for (int i = t; i < RSZ; i += 256) dst_p[i] = h[i];
}

// ---- scan1: reduce partials -> norms + block-local exclusive scan ----------
__global__ __launch_bounds__(256) void scan1_kernel(
    const unsigned* __restrict__ partial_s, const unsigned* __restrict__ partial_d,
    int* __restrict__ row_off, int* __restrict__ blk_sums,
    float* __restrict__ norm_src, float* __restrict__ norm_dst, int N)
{
    __shared__ int s[256];
    const int t = threadIdx.x;
    const int base = blockIdx.x * 1024 + t * 4;

    unsigned ss0 = 0, ss1 = 0, ss2 = 0, ss3 = 0;
    unsigned sd0 = 0, sd1 = 0, sd2 = 0, sd3 = 0;
    {
        // base..base+3 never cross an RSZ boundary (both multiples of 4)
        const int r = base / RSZ;
        const int off = base & (RSZ - 1);
        const unsigned* ps = partial_s + (size_t)r * NSL * RSZ + off;
        const unsigned* pd = partial_d + (size_t)r * NSL * RSZ + off;
        #pragma unroll
        for (int sl = 0; sl < NSL; ++sl) {
            uint4 a = *(const uint4*)(ps + (size_t)sl * RSZ);
            uint4 b = *(const uint4*)(pd + (size_t)sl * RSZ);
            ss0 += a.x; ss1 += a.y; ss2 += a.z; ss3 += a.w;
            sd0 += b.x; sd1 += b.y; sd2 += b.z; sd3 += b.w;
        }
    }
    if (base + 0 < N) {
        norm_src[base + 0] = ss0 ? 1.0f / sqrtf((float)ss0) : 0.0f;
        norm_dst[base + 0] = sd0 ? 1.0f / sqrtf((float)sd0) : 0.0f;
    }
    if (base + 1 < N) {
        norm_src[base + 1] = ss1 ? 1.0f / sqrtf((float)ss1) : 0.0f;
        norm_dst[base + 1] = sd1 ? 1.0f / sqrtf((float)sd1) : 0.0f;
    }
    if (base + 2 < N) {
        norm_src[base + 2] = ss2 ? 1.0f / sqrtf((float)ss2) : 0.0f;
        norm_dst[base + 2] = sd2 ? 1.0f / sqrtf((float)sd2) : 0.0f;
    }
    if (base + 3 < N) {
        norm_src[base + 3] = ss3 ? 1.0f / sqrtf((float)ss3) : 0.0f;
        norm_dst[base + 3] = sd3 ? 1.0f / sqrtf((float)sd3) : 0.0f;
    }

    int v0 = (base + 0 < N) ? (int)sd0 : 0;
    int v1 = (base + 1 < N) ? (int)sd1 : 0;
    int v2 = (base + 2 < N) ? (int)sd2 : 0;
    int v3 = (base + 3 < N) ? (int)sd3 : 0;
    int local = v0 + v1 + v2 + v3;
    s[t] = local;
    __syncthreads();
    for (int off = 1; off < 256; off <<= 1) {
        int x = (t >= off) ? s[t - off] : 0;
        __syncthreads();
        s[t] += x;
        __syncthreads();
    }
    int excl = s[t] - local;
    if (t == 255) blk_sums[blockIdx.x] = s[t];
    if (base + 0 < N) row_off[base + 0] = excl;
    if (base + 1 < N) row_off[base + 1] = excl + v0;
    if (base + 2 < N) row_off[base + 2] = excl + v0 + v1;
    if (base + 3 < N) row_off[base + 3] = excl + v0 + v1 + v2;
}

// ---- scan2 (block 0) + pack W1->W1t (blocks 1..128) + W2->W2t (129..152) ---
// W1t [128][256] bf16 n-major k-contig; W2t [48][128] fp16 n-major k-contig
// (rows 40..47 zero) -- both match the gemm1/MFMA B-frag layout.
__global__ __launch_bounds__(256) void scan2_pack_kernel(
    int* __restrict__ blk_sums, int B,
    const float* __restrict__ W1, __hip_bfloat16* __restrict__ W1t,
    const float* __restrict__ W2, unsigned short* __restrict__ W2t)
{
    const int t = threadIdx.x;
    if (blockIdx.x > 128) {
        int idx = (blockIdx.x - 129) * 256 + t;   // 0..6143
        int n = idx >> 7;                         // 0..47
        int k = idx & 127;
        W2t[idx] = (n < F_CLS) ? f2h(W2[(size_t)k * F_CLS + n]) : (unsigned short)0;
        return;
    }
    if (blockIdx.x > 0) {
        int idx = (blockIdx.x - 1) * 256 + t;     // 0..32767
        int n = idx >> 8;
        int k = idx & 255;
        W1t[idx] = __float2bfloat16(W1[(size_t)k * F_HID + n]);
        return;
    }
    __shared__ int s[256];
    int local = (t < B) ? blk_sums[t] : 0;
    s[t] = local;
    __syncthreads();
    for (int off = 1; off < 256; off <<= 1) {
        int x = (t >= off) ? s[t - off] : 0;
        __syncthreads();
        s[t] += x;
        __syncthreads();
    }
    if (t < B) blk_sums[t] = s[t] - local;   // exclusive
}

// ---- scan3+slicepref fused: finalize row_off and convert partial_d counts
//      into absolute CSR cursors (in-place exclusive scan over slices) -------
__global__ __launch_bounds__(256) void scan3_slicepref_kernel(
    int* __restrict__ row_off, const int* __restrict__ blk_sums,
    unsigned* __restrict__ partial_d, int N, int E, int NRtot)
{
    const int idx = blockIdx.x * 256 + threadIdx.x;   // node id (incl. pad)
    if (idx >= NRtot) return;
    unsigned run = 0;
    if (idx < N) {
        int v = row_off[idx] + blk_sums[idx >> 10];
        row_off[idx] = v;
        run = (unsigned)v;
    }
    if (idx == N) row_off[N] = E;
    const int r = idx / RSZ;
    const int i = idx & (RSZ - 1);
    unsigned* p = partial_d + (size_t)r * NSL * RSZ + i;
    #pragma unroll
    for (int sl = 0; sl < NSL; ++sl) {
        unsigned c = p[(size_t)sl * RSZ];
        p[(size_t)sl * RSZ] = run;
        run += c;
    }
}

// ---- scatter edges into CSR via LDS cursors (no global atomics) ------------
__global__ __launch_bounds__(256) void scatter2_kernel(
    const int* __restrict__ src, const int* __restrict__ dst,
    const unsigned* __restrict__ pref, int* __restrict__ csr_src, int E)
{
    __shared__ unsigned cur[RSZ];
    const int t = threadIdx.x;
    const int r  = blockIdx.x / NSL;
    const int sl = blockIdx.x % NSL;
    const int lo = r * RSZ;
    const unsigned* p = pref + (size_t)blockIdx.x * RSZ;   // [r][sl][.]

    for (int i = t; i < RSZ; i += 256) cur[i] = p[i];
    __syncthreads();

    const int slice = (E + NSL - 1) / NSL;
    const int e0 = sl * slice;
    const int e1 = min(E, e0 + slice);

    int e = e0 + t;
    for (; e + 7 * 256 < e1; e += 8 * 256) {
        int d[8], s[8];
        #pragma unroll
        for (int i = 0; i < 8; ++i) { d[i] = dst[e + i * 256]; s[i] = src[e + i * 256]; }
        #pragma unroll
        for (int i = 0; i < 8; ++i) {
            unsigned k = (unsigned)(d[i] - lo);
            if (k < RSZ) {
                unsigned pos = atomicAdd(&cur[k], 1u);
                csr_src[pos] = s[i];
            }
        }
    }
    for (; e < e1; e += 256) {
        unsigned k = (unsigned)(dst[e] - lo);
        if (k < RSZ) {
            unsigned pos = atomicAdd(&cur[k], 1u);
            csr_src[pos] = src[e];
        }
    }
}

// ---- GEMM1 (MFMA): h1b[N,128] = bf16( (X @ W1)*ns ) ------------------------
// R12 structure + R19 latency fixes: BM=128, 512 threads (8 waves), full
// W1t (64KB) staged to LDS once (XOR-swizzled, conflict-free ds_read_b128),
// one barrier. 2-deep X prefetch; ns applied in the fp32 epilogue.
__global__ __launch_bounds__(512, 4) void gemm1_mfma_kernel(
    const float* __restrict__ X, const __hip_bfloat16* __restrict__ W1t,
    const float* __restrict__ norm_src, __hip_bfloat16* __restrict__ h1b, int N)
{
    __shared__ __hip_bfloat16 Bs[128 * 256];   // 64KB, rows XOR-swizzled
    const int t = threadIdx.x;
    const int node0 = blockIdx.x * 128;
    const int lane = t & 63;
    const int w = t >> 6;               // wave 0..7 -> 16 rows each
    const int l15 = lane & 15;
    const int quad = lane >> 4;

    const int arow = node0 + w * 16 + l15;
    const int arow_c = (arow < N) ? arow : (N - 1);
    const float* xp = X + (size_t)arow_c * F_IN + quad * 8;

    // 2-deep prefetch: chunks 0,1 resolve under the 64KB stage + barrier
    float4 ar[2][4];
    ar[0][0] = *(const float4*)(xp + 0);
    ar[0][1] = *(const float4*)(xp + 4);
    ar[0][2] = *(const float4*)(xp + 32);
    ar[0][3] = *(const float4*)(xp + 36);
    ar[1][0] = *(const float4*)(xp + 64 + 0);
    ar[1][1] = *(const float4*)(xp + 64 + 4);
    ar[1][2] = *(const float4*)(xp + 64 + 32);
    ar[1][3] = *(const float4*)(xp + 64 + 36);

    // stage W1t[128][256] -> LDS, reg-staged so dest can carry the XOR swizzle
    #pragma unroll
    for (int i = 0; i < 8; ++i) {
        int idx = i * 512 + t;
        int row = idx >> 5;             // 0..127
        int ch  = idx & 31;             // 16B chunk within row
        uint4 v = *(const uint4*)(W1t + (size_t)row * F_IN + ch * 8);
        int d = row * 256 + ((ch * 8) ^ ((row & 7) << 3));
        *(uint4*)(Bs + d) = v;
    }
    __syncthreads();

    const int swz = (l15 & 7) << 3;
    const int bbase0 = l15 * 256 + ((quad * 8) ^ swz);
    const int bbase1 = l15 * 256 + ((32 + quad * 8) ^ swz);

    floatx4 acc[8] = {};

    #pragma unroll
    for (int c = 0; c < 4; ++c) {
        const int p = c & 1;
        bf16x8 ab0, ab1;
        {
            union { bf16x8 v; unsigned short u[8]; } cv;
            cv.u[0] = f2b(ar[p][0].x); cv.u[1] = f2b(ar[p][0].y);
            cv.u[2] = f2b(ar[p][0].z); cv.u[3] = f2b(ar[p][0].w);
            cv.u[4] = f2b(ar[p][1].x); cv.u[5] = f2b(ar[p][1].y);
            cv.u[6] = f2b(ar[p][1].z); cv.u[7] = f2b(ar[p][1].w);
            ab0 = cv.v;
            cv.u[0] = f2b(ar[p][2].x); cv.u[1] = f2b(ar[p][2].y);
            cv.u[2] = f2b(ar[p][2].z); cv.u[3] = f2b(ar[p][2].w);
            cv.u[4] = f2b(ar[p][3].x); cv.u[5] = f2b(ar[p][3].y);
            cv.u[6] = f2b(ar[p][3].z); cv.u[7] = f2b(ar[p][3].w);
            ab1 = cv.v;
        }
        if (c < 2) {
            ar[p][0] = *(const float4*)(xp + (c + 2) * 64 + 0);
            ar[p][1] = *(const float4*)(xp + (c + 2) * 64 + 4);
            ar[p][2] = *(const float4*)(xp + (c + 2) * 64 + 32);
            ar[p][3] = *(const float4*)(xp + (c + 2) * 64 + 36);
        }
        #pragma unroll
        for (int nt = 0; nt < 8; ++nt) {
            bf16x8 b = *(const bf16x8*)(Bs + bbase0 + nt * 16 * 256 + c * 64);
            acc[nt] = __builtin_amdgcn_mfma_f32_16x16x32_bf16(ab0, b, acc[nt], 0, 0, 0);
        }
        #pragma unroll
        for (int nt = 0; nt < 8; ++nt) {
            bf16x8 b = *(const bf16x8*)(Bs + bbase1 + nt * 16 * 256 + c * 64);
            acc[nt] = __builtin_amdgcn_mfma_f32_16x16x32_bf16(ab1, b, acc[nt], 0, 0, 0);
        }
    }

    // epilogue: ns of the OUTPUT row (C row = w*16 + quad*4 + r), fp32
    #pragma unroll
    for (int r = 0; r < 4; ++r) {
        int node = node0 + w * 16 + quad * 4 + r;
        if (node < N) {
            float ns = norm_src[node];
            #pragma unroll
            for (int nt = 0; nt < 8; ++nt)
                h1b[(size_t)node * F_HID + nt * 16 + l15] =
                    __float2bfloat16(acc[nt][r] * ns);
        }
    }
}

// ---- SpMM1 + layer-1 epilogue + fused MFMA projection to h2 ----------------
// 16 nodes/block (512 thr), 32 lanes/node: gather h1b rows, activate, store
// fp16 row to LDS As[16][136]. Then wave 0 computes h2[16 nodes][40] =
// As @ W2t via 12x mfma_f32_16x16x32_f16.
__global__ __launch_bounds__(512) void spmm1_fused_kernel(
    const __hip_bfloat16* __restrict__ h1b, const int* __restrict__ row_off,
    const int* __restrict__ csr_src, const float* __restrict__ norm_src,
    const float* __restrict__ norm_dst, const float* __restrict__ b1,
    const unsigned short* __restrict__ W2t, unsigned short* __restrict__ h2, int N)
{
    __shared__ unsigned short As[16][136];
    const int t = threadIdx.x;
    const int g = t >> 5;
    const int node = blockIdx.x * 16 + g;
    const int c = (t & 31) << 2;

    if (node < N) {
        const int start = row_off[node];
        const int end = row_off[node + 1];
        float4 acc = make_float4(0.f, 0.f, 0.f, 0.f);
        int j = start;
        for (; j + 8 <= end; j += 8) {
            int s[8];
            #pragma unroll
            for (int i = 0; i < 8; ++i) s[i] = csr_src[j + i];
            ushort4 u[8];
            #pragma unroll
            for (int i = 0; i < 8; ++i)
                u[i] = *(const ushort4*)(h1b + (size_t)s[i] * F_HID + c);
            #pragma unroll
            for (int i = 0; i < 8; ++i) {
                acc.x += b2f(u[i].x);
                acc.y += b2f(u[i].y);
                acc.z += b2f(u[i].z);
                acc.w += b2f(u[i].w);
            }
        }
        for (; j + 2 <= end; j += 2) {
            int s0 = csr_src[j + 0];
            int s1 = csr_src[j + 1];
            ushort4 u0 = *(const ushort4*)(h1b + (size_t)s0 * F_HID + c);
            ushort4 u1 = *(const ushort4*)(h1b + (size_t)s1 * F_HID + c);
            acc.x += b2f(u0.x) + b2f(u1.x);
            acc.y += b2f(u0.y) + b2f(u1.y);
            acc.z += b2f(u0.z) + b2f(u1.z);
            acc.w += b2f(u0.w) + b2f(u1.w);
        }
        if (j < end) {
            int s = csr_src[j];
            ushort4 u = *(const ushort4*)(h1b + (size_t)s * F_HID + c);
            acc.x += b2f(u.x);
            acc.y += b2f(u.y);
            acc.z += b2f(u.z);
            acc.w += b2f(u.w);
        }
        const float nd = norm_dst[node];
        const float ns = norm_src[node];
        float4 bb = *(const float4*)(b1 + c);
        ushort4 o;
        o.x = f2h(fmaxf(fmaf(acc.x, nd, bb.x), 0.f) * ns);
        o.y = f2h(fmaxf(fmaf(acc.y, nd, bb.y), 0.f) * ns);
        o.z = f2h(fmaxf(fmaf(acc.z, nd, bb.z), 0.f) * ns);
        o.w = f2h(fmaxf(fmaf(acc.w, nd, bb.w), 0.f) * ns);
        *(ushort4*)&As[g][c] = o;
    } else {
        ushort4 z = make_ushort4(0, 0, 0, 0);
        *(ushort4*)&As[g][c] = z;
    }
    __syncthreads();
    if (t >= 64) return;

    const int l15 = t & 15;
    const int quad = t >> 4;
    floatx4 co[3] = {};
    #pragma unroll
    for (int kc = 0; kc < 4; ++kc) {
        f16x8 a = *(const f16x8*)&As[l15][kc * 32 + quad * 8];
        #pragma unroll
        for (int ct = 0; ct < 3; ++ct) {
            f16x8 b = *(const f16x8*)(W2t + (size_t)(ct * 16 + l15) * F_HID
                                          + kc * 32 + quad * 8);
            co[ct] = __builtin_amdgcn_mfma_f32_16x16x32_f16(a, b, co[ct], 0, 0, 0);
        }
    }
    const int node0 = blockIdx.x * 16;
    #pragma unroll
    for (int ct = 0; ct < 3; ++ct) {
        int col = ct * 16 + l15;
        if (col < F_CLS) {
            #pragma unroll
            for (int i = 0; i < 4; ++i) {
                int n2 = node0 + quad * 4 + i;
                if (n2 < N) h2[(size_t)n2 * F_CLS + col] = f2h(co[ct][i]);
            }
        }
    }
}

// ---- SpMM2 (CSR, fp16 gather) + epilogue: out = (sum h2[src,:])*nd + b2 ----
// 25 nodes/block, 10 lanes/node (250/256 active), 8-deep gather batching.
__global__ __launch_bounds__(256) void spmm2_csr_kernel(
    const unsigned short* __restrict__ h2, const int* __restrict__ row_off,
    const int* __restrict__ csr_src, const float* __restrict__ norm_dst,
    const float* __restrict__ b2, float* __restrict__ out, int N)
{
    const int t = threadIdx.x;
    if (t >= 250) return;
    const int node = blockIdx.x * 25 + t / 10;
    const int lane = t % 10;
    if (node >= N) return;
    const int c = lane << 2;
    const int start = row_off[node];
    const int end = row_off[node + 1];
    float4 acc = make_float4(0.f, 0.f, 0.f, 0.f);
    int j = start;
    for (; j + 8 <= end; j += 8) {
        int s[8];
        #pragma unroll
        for (int i = 0; i < 8; ++i) s[i] = csr_src[j + i];
        ushort4 u[8];
        #pragma unroll
        for (int i = 0; i < 8; ++i)
            u[i] = *(const ushort4*)(h2 + (size_t)s[i] * F_CLS + c);
        #pragma unroll
        for (int i = 0; i < 8; ++i) {
            acc.x += h2f(u[i].x);
            acc.y += h2f(u[i].y);
            acc.z += h2f(u[i].z);
            acc.w += h2f(u[i].w);
        }
    }
    for (; j + 2 <= end; j += 2) {
        int s0 = csr_src[j + 0];
        int s1 = csr_src[j + 1];
        ushort4 u0 = *(const ushort4*)(h2 + (size_t)s0 * F_CLS + c);
        ushort4 u1 = *(const ushort4*)(h2 + (size_t)s1 * F_CLS + c);
        acc.x += h2f(u0.x) + h2f(u1.x);
        acc.y += h2f(u0.y) + h2f(u1.y);
        acc.z += h2f(u0.z) + h2f(u1.z);
        acc.w += h2f(u0.w) + h2f(u1.w);
    }
    if (j < end) {
        int s = csr_src[j];
        ushort4 u = *(const ushort4*)(h2 + (size_t)s * F_CLS + c);
        acc.x += h2f(u.x);
        acc.y += h2f(u.y);
        acc.z += h2f(u.z);
        acc.w += h2f(u.w);
    }
    float nd = norm_dst[node];
    float4 bb = *(const float4*)(b2 + c);
    float4 r;
    r.x = fmaf(acc.x, nd, bb.x);
    r.y = fmaf(acc.y, nd, bb.y);
    r.z = fmaf(acc.z, nd, bb.z);
    r.w = fmaf(acc.w, nd, bb.w);
    *(float4*)(out + (size_t)node * F_CLS + c) = r;
}

extern "C" void kernel_launch(void* const* d_in, const int* in_sizes, int n_in,
                              void* d_out, int out_size, void* d_ws, size_t ws_size,
                              hipStream_t stream) {
    const float* X   = (const float*)d_in[0];
    const int*   src = (const int*)d_in[1];
    const int*   dst = (const int*)d_in[2];
    const float* W1  = (const float*)d_in[3];
    const float* b1  = (const float*)d_in[4];
    const float* W2  = (const float*)d_in[5];
    const float* b2  = (const float*)d_in[6];
    float* out = (float*)d_out;

    const int N = in_sizes[0] / F_IN;
    const int E = in_sizes[1];
    const int NB = (N + 1023) / 1024;     // scan blocks (<= 256)
    const int NR = (N + RSZ - 1) / RSZ;   // histogram ranges
    const int NRtot = NR * RSZ;

    // workspace layout — keep every array 16B-aligned
    char* w = (char*)d_ws;
    int*   row_off  = (int*)w;                      w += (size_t)(N + 4) * 4;
    int*   blk_sums = (int*)w;                      w += 256 * 4;
    int*   csr_src  = (int*)w;                      w += (size_t)E * 4;
    float* norm_src = (float*)w;                    w += (size_t)N * 4;
    float* norm_dst = (float*)w;                    w += (size_t)N * 4;
    unsigned short* h2 = (unsigned short*)w;        w += (size_t)N * F_CLS * 2;
    __hip_bfloat16* W1t = (__hip_bfloat16*)w;       w += (size_t)F_HID * F_IN * 2;
    unsigned short* W2t = (unsigned short*)w;       w += (size_t)48 * F_HID * 2;
    __hip_bfloat16* h1b = (__hip_bfloat16*)w;       w += (size_t)N * F_HID * 2;
    unsigned* partial_s = (unsigned*)w;             w += (size_t)NR * NSL * RSZ * 4;
    unsigned* partial_d = (unsigned*)w;             w += (size_t)NR * NSL * RSZ * 4;

    hist_kernel<<<dim3(NR * NSL, 2), 256, 0, stream>>>(src, dst, partial_s, partial_d, E);

    scan1_kernel<<<NB, 256, 0, stream>>>(partial_s, partial_d, row_off, blk_sums,
                                         norm_src, norm_dst, N);
    scan2_pack_kernel<<<153, 256, 0, stream>>>(blk_sums, NB, W1, W1t, W2, W2t);
    scan3_slicepref_kernel<<<(NRtot + 255) / 256, 256, 0, stream>>>(
        row_off, blk_sums, partial_d, N, E, NRtot);

    scatter2_kernel<<<NR * NSL, 256, 0, stream>>>(src, dst, partial_d, csr_src, E);

    gemm1_mfma_kernel<<<(N + 127) / 128, 512, 0, stream>>>(X, W1t, norm_src, h1b, N);

    spmm1_fused_kernel<<<(N + 15) / 16, 512, 0, stream>>>(h1b, row_off, csr_src,
                                                          norm_src, norm_dst, b1,
                                                          W2t, h2, N);

    spmm2_csr_kernel<<<(N + 24) / 25, 256, 0, stream>>>(h2, row_off, csr_src,
                                                        norm_dst, b2, out, N);
}